// Round 12
// baseline (426.900 us; speedup 1.0000x reference)
//
#include <hip/hip_runtime.h>
#include <hip/hip_bf16.h>
#include <math.h>

#define NN 50000
#define NE 500000
#define NG 64
#define DIN 64
#define DE 8
#define HD 128
#define TFD 2000
#define NSD 10
#define NL 3
#define CDIM 544
#define LN_EPS 1e-5f
#define NSTRIP 3125  // 50000 / 16
#define PCH 32
#define NTILES 49    // ceil(50000/1024)
#define MM_GRID 782  // 782*4 = 3128 waves >= 3125 strips

// pre-swizzled bf16 weight buffer offsets (in u16 elements)
#define OFF_IN 0
#define OFF_W1 8192
#define OFF_W2 57344
#define OFF_JK 106496
#define WPRE_TOTAL 114688
#define CNT_BLOCKS 977   // ceil(NE/2/256) for k_prep count half (2 edges/thread)
#define WCVT_BLOCKS 448  // ceil(WPRE_TOTAL/256)
#define TEK 64
#define TE_BLOCKS 32     // 32*64 = 2048 >= TFD

typedef float f32x4 __attribute__((ext_vector_type(4)));
typedef short short8 __attribute__((ext_vector_type(8)));
typedef __bf16 bf16x8_t __attribute__((ext_vector_type(8)));
typedef unsigned short u16;

__device__ __forceinline__ short f2bf(float f) {
  unsigned u = __builtin_bit_cast(unsigned, f);
  u += 0x7fffu + ((u >> 16) & 1u);
  return (short)(u >> 16);
}

__device__ __forceinline__ float bflo(unsigned v) {
  return __builtin_bit_cast(float, v << 16);
}
__device__ __forceinline__ float bfhi(unsigned v) {
  return __builtin_bit_cast(float, v & 0xffff0000u);
}
__device__ __forceinline__ float bf1(u16 v) {
  return __builtin_bit_cast(float, (unsigned)v << 16);
}

__device__ __forceinline__ f32x4 MFMA(short8 a, short8 b, f32x4 c) {
  return __builtin_amdgcn_mfma_f32_16x16x32_bf16(
      __builtin_bit_cast(bf16x8_t, a), __builtin_bit_cast(bf16x8_t, b), c, 0, 0, 0);
}

// ---------------- fused: edge count (2 edges/thread) + weight pre-convert ----------------
__global__ void k_prep(const int* __restrict__ dst, int* __restrict__ cnt,
                       const float* __restrict__ w_in, const float* __restrict__ conv_w1,
                       const float* __restrict__ conv_w2, const float* __restrict__ jk_w1,
                       u16* __restrict__ wpre) {
  int b = blockIdx.x;
  if (b < CNT_BLOCKS) {
    int e = (b * 256 + threadIdx.x) * 2;
    if (e < NE) atomicAdd(&cnt[dst[e]], 1);
    if (e + 1 < NE) atomicAdd(&cnt[dst[e + 1]], 1);
    return;
  }
  int i = (b - CNT_BLOCKS) * 256 + threadIdx.x;
  if (i >= WPRE_TOTAL) return;
  if (i < OFF_W1) {
    int c = i & 127, k = i >> 7;  // k 0..63
    wpre[OFF_IN + c * 64 + (k ^ ((c & 7) << 3))] = (u16)f2bf(w_in[(size_t)k * 128 + c]);
  } else if (i < OFF_W2) {
    int i2 = i - OFF_W1;
    int l = i2 >> 14, r = i2 & 16383;
    int c = r & 127, k = r >> 7;
    wpre[OFF_W1 + l * 16384 + c * 128 + (k ^ ((c & 7) << 3))] =
        (u16)f2bf(conv_w1[(size_t)l * 16384 + k * 128 + c]);
  } else if (i < OFF_JK) {
    int i2 = i - OFF_W2;
    int l = i2 >> 14, r = i2 & 16383;
    int c = r & 127, k = r >> 7;
    wpre[OFF_W2 + l * 16384 + c * 128 + (k ^ ((c & 7) << 3))] =
        (u16)f2bf(conv_w2[(size_t)l * 16384 + k * 128 + c]);
  } else {
    int i2 = i - OFF_JK;
    int c = i2 & 63, k = i2 >> 6;  // k 0..127
    wpre[OFF_JK + c * 128 + (k ^ ((c & 7) << 3))] = (u16)f2bf(jk_w1[(size_t)k * 64 + c]);
  }
}

// ---------------- tfidf split-K GEMM: teacc += tfidf_chunk @ w_chunk ----------------
__global__ __launch_bounds__(256) void k_te1(const float* __restrict__ tfidf,
                                             const float* __restrict__ w,
                                             float* __restrict__ teacc) {
  __shared__ float wch[TEK][129];
  __shared__ float tch[64][65];
  int k0 = blockIdx.x * TEK;
  int t = threadIdx.x;
  for (int i = t; i < TEK * 128; i += 256) {
    int k = i >> 7, c = i & 127;
    int kk = k0 + k;
    wch[k][c] = (kk < TFD) ? w[(size_t)kk * HD + c] : 0.f;
  }
  for (int i = t; i < 64 * TEK; i += 256) {
    int g = i >> 6, k = i & 63;
    int kk = k0 + k;
    tch[g][k] = (kk < TFD) ? tfidf[(size_t)g * TFD + kk] : 0.f;
  }
  __syncthreads();
  int c = t & 127, gh = t >> 7;
  for (int g = gh * 32; g < gh * 32 + 32; ++g) {
    float acc = 0.f;
#pragma unroll 8
    for (int k = 0; k < TEK; ++k) acc = fmaf(tch[g][k], wch[k][c], acc);
    atomicAdd(&teacc[g * HD + c], acc);
  }
}

// ---------------- CSR scan ----------------
__global__ __launch_bounds__(256) void k_scan1(const int* __restrict__ cnt,
                                               int* __restrict__ rowptr,
                                               int* __restrict__ tileSum) {
  __shared__ int wsum[4];
  int tile = blockIdx.x;
  int base = tile * 1024;
  int t = threadIdx.x, lane = t & 63, wave = t >> 6;
  int idx = base + t * 4;
  int4 v = make_int4(0, 0, 0, 0);
  if (idx + 3 < NN) {
    v = *(const int4*)(cnt + idx);
  } else if (idx < NN) {
    v.x = cnt[idx];
    v.y = (idx + 1 < NN) ? cnt[idx + 1] : 0;
    v.z = (idx + 2 < NN) ? cnt[idx + 2] : 0;
    v.w = (idx + 3 < NN) ? cnt[idx + 3] : 0;
  }
  int s = v.x + v.y + v.z + v.w;
  int incl = s;
#pragma unroll
  for (int o = 1; o < 64; o <<= 1) {
    int n = __shfl_up(incl, o);
    if (lane >= o) incl += n;
  }
  if (lane == 63) wsum[wave] = incl;
  __syncthreads();
  int wbase = 0;
  for (int w = 0; w < wave; ++w) wbase += wsum[w];
  int ex = wbase + incl - s;
  if (idx < NN) rowptr[idx] = ex;
  if (idx + 1 < NN) rowptr[idx + 1] = ex + v.x;
  if (idx + 2 < NN) rowptr[idx + 2] = ex + v.x + v.y;
  if (idx + 3 < NN) rowptr[idx + 3] = ex + v.x + v.y + v.z;
  if (t == 255) tileSum[tile] = wbase + incl;
}

__global__ __launch_bounds__(64) void k_scan2(const int* __restrict__ tileSum,
                                              int* __restrict__ tileOff,
                                              int* __restrict__ rowptr) {
  int t = threadIdx.x;
  int v = (t < NTILES) ? tileSum[t] : 0;
  int incl = v;
#pragma unroll
  for (int o = 1; o < 64; o <<= 1) {
    int n = __shfl_up(incl, o);
    if (t >= o) incl += n;
  }
  if (t < NTILES) tileOff[t] = incl - v;
  if (t == 63) rowptr[NN] = incl;
}

__global__ void k_scan3(const int* __restrict__ tileOff, int* __restrict__ rowptr,
                        int* __restrict__ nextp) {
  int i = blockIdx.x * 256 + threadIdx.x;
  if (i < NN) {
    int v = rowptr[i] + tileOff[i >> 10];
    rowptr[i] = v;
    nextp[i] = v;
  }
}

// fill: counting-sort by dst -> src_perm + CSR-ordered bf16 edge attrs (2 edges/thread)
__global__ void k_fill(const int* __restrict__ src, const int* __restrict__ dst,
                       const float* __restrict__ eattr, int* __restrict__ nextp,
                       int* __restrict__ src_perm, u16* __restrict__ attr_bf) {
  int e = (blockIdx.x * 256 + threadIdx.x) * 2;
  if (e >= NE) return;
  int d0 = dst[e];
  int s0 = src[e];
  const float4* a0p = (const float4*)(eattr + (size_t)e * DE);
  float4 a00 = a0p[0], a01 = a0p[1];
  bool has1 = (e + 1 < NE);
  int d1 = 0, s1 = 0;
  float4 a10, a11;
  if (has1) {
    d1 = dst[e + 1];
    s1 = src[e + 1];
    const float4* a1p = (const float4*)(eattr + (size_t)(e + 1) * DE);
    a10 = a1p[0];
    a11 = a1p[1];
  }
  int pos0 = atomicAdd(&nextp[d0], 1);
  int pos1 = has1 ? atomicAdd(&nextp[d1], 1) : 0;
  src_perm[pos0] = s0;
  uint4 w0;
  w0.x = (unsigned)(u16)f2bf(a00.x) | ((unsigned)(u16)f2bf(a00.y) << 16);
  w0.y = (unsigned)(u16)f2bf(a00.z) | ((unsigned)(u16)f2bf(a00.w) << 16);
  w0.z = (unsigned)(u16)f2bf(a01.x) | ((unsigned)(u16)f2bf(a01.y) << 16);
  w0.w = (unsigned)(u16)f2bf(a01.z) | ((unsigned)(u16)f2bf(a01.w) << 16);
  *(uint4*)(attr_bf + (size_t)pos0 * DE) = w0;
  if (has1) {
    src_perm[pos1] = s1;
    uint4 w1;
    w1.x = (unsigned)(u16)f2bf(a10.x) | ((unsigned)(u16)f2bf(a10.y) << 16);
    w1.y = (unsigned)(u16)f2bf(a10.z) | ((unsigned)(u16)f2bf(a10.w) << 16);
    w1.z = (unsigned)(u16)f2bf(a11.x) | ((unsigned)(u16)f2bf(a11.y) << 16);
    w1.w = (unsigned)(u16)f2bf(a11.z) | ((unsigned)(u16)f2bf(a11.w) << 16);
    *(uint4*)(attr_bf + (size_t)pos1 * DE) = w1;
  }
}

// EAGG[node] = sum over incoming edges of relu(attr @ w_e + b_e)
__device__ __forceinline__ void eagg_body(uint4 aw, const float2* wv, float2 be2,
                                          float& ax, float& ay) {
  float a[8] = {bflo(aw.x), bfhi(aw.x), bflo(aw.y), bfhi(aw.y),
                bflo(aw.z), bfhi(aw.z), bflo(aw.w), bfhi(aw.w)};
  float ex = be2.x, ey = be2.y;
#pragma unroll
  for (int k = 0; k < 8; ++k) {
    ex = fmaf(a[k], wv[k].x, ex);
    ey = fmaf(a[k], wv[k].y, ey);
  }
  ax += fmaxf(ex, 0.f);
  ay += fmaxf(ey, 0.f);
}

__global__ __launch_bounds__(256) void k_eagg(const int* __restrict__ rowptr,
                                              const u16* __restrict__ attr_bf,
                                              const float* __restrict__ we,
                                              const float* __restrict__ be,
                                              u16* __restrict__ eagg) {
  int t = threadIdx.x;
  int wave = t >> 6, lane = t & 63;
  float2 wv[8];
#pragma unroll
  for (int k = 0; k < 8; ++k) wv[k] = ((const float2*)(we + k * HD))[lane];
  float2 be2 = ((const float2*)be)[lane];
  int node = blockIdx.x * 4 + wave;
  if (node >= NN) return;
  int p0 = rowptr[node], p1 = rowptr[node + 1];
  float ax = 0.f, ay = 0.f;
  int p = p0;
  for (; p + 3 < p1; p += 4) {
    uint4 w0 = *(const uint4*)(attr_bf + (size_t)p * DE);
    uint4 w1 = *(const uint4*)(attr_bf + (size_t)(p + 1) * DE);
    uint4 w2 = *(const uint4*)(attr_bf + (size_t)(p + 2) * DE);
    uint4 w3 = *(const uint4*)(attr_bf + (size_t)(p + 3) * DE);
    eagg_body(w0, wv, be2, ax, ay);
    eagg_body(w1, wv, be2, ax, ay);
    eagg_body(w2, wv, be2, ax, ay);
    eagg_body(w3, wv, be2, ax, ay);
  }
  for (; p < p1; ++p) {
    uint4 w0 = *(const uint4*)(attr_bf + (size_t)p * DE);
    eagg_body(w0, wv, be2, ax, ay);
  }
  unsigned w = (unsigned)(u16)f2bf(ax) | ((unsigned)(u16)f2bf(ay) << 16);
  *(unsigned*)(eagg + (size_t)node * HD + 2 * lane) = w;
}

// ---------------- MFMA matmul (f32 A, input layer) + BN column stats ----------------
template <int KD>
__global__ __launch_bounds__(256) void k_mm1f(const float* __restrict__ A,
                                              const u16* __restrict__ Wswz,
                                              u16* __restrict__ T,
                                              float* __restrict__ stats) {
  constexpr int KCH = KD / 32;
  __shared__ short wt[128 * KD];
  __shared__ float sred[256];
  int t = threadIdx.x;
  {
    const uint4* ws = (const uint4*)Wswz;
    uint4* wd = (uint4*)wt;
#pragma unroll
    for (int i = t; i < 128 * KD / 8; i += 256) wd[i] = ws[i];
  }
  sred[t] = 0.f;
  __syncthreads();
  int wave = t >> 6, lane = t & 63;
  int r0 = lane & 15, kg = lane >> 4;
  float cs[8], cq[8];
#pragma unroll
  for (int n = 0; n < 8; ++n) { cs[n] = 0.f; cq[n] = 0.f; }
  int strip = blockIdx.x * 4 + wave;
  if (strip < NSTRIP) {
    const float* arow = A + (size_t)(strip * 16 + r0) * KD + kg * 8;
    short8 af[KCH];
#pragma unroll
    for (int kk = 0; kk < KCH; ++kk) {
      float4 a0 = *(const float4*)(arow + kk * 32);
      float4 a1 = *(const float4*)(arow + kk * 32 + 4);
      short8 v;
      v[0] = f2bf(a0.x); v[1] = f2bf(a0.y); v[2] = f2bf(a0.z); v[3] = f2bf(a0.w);
      v[4] = f2bf(a1.x); v[5] = f2bf(a1.y); v[6] = f2bf(a1.z); v[7] = f2bf(a1.w);
      af[kk] = v;
    }
    f32x4 acc[8];
#pragma unroll
    for (int n = 0; n < 8; ++n) acc[n] = (f32x4){0.f, 0.f, 0.f, 0.f};
#pragma unroll
    for (int kk = 0; kk < KCH; ++kk) {
      int kb = kk * 32 + kg * 8;
#pragma unroll
      for (int n = 0; n < 8; ++n) {
        int c = n * 16 + r0;
        short8 bf = *(const short8*)(wt + c * KD + (kb ^ ((c & 7) << 3)));
        acc[n] = MFMA(af[kk], bf, acc[n]);
      }
    }
    u16* trow = T + (size_t)(strip * 16 + kg * 4) * HD;
#pragma unroll
    for (int n = 0; n < 8; ++n) {
#pragma unroll
      for (int j = 0; j < 4; ++j) {
        float v = acc[n][j];
        trow[(size_t)j * HD + n * 16 + r0] = (u16)f2bf(v);
        cs[n] += v;
        cq[n] = fmaf(v, v, cq[n]);
      }
    }
  }
#pragma unroll
  for (int n = 0; n < 8; ++n) {
    cs[n] += __shfl_xor(cs[n], 16); cs[n] += __shfl_xor(cs[n], 32);
    cq[n] += __shfl_xor(cq[n], 16); cq[n] += __shfl_xor(cq[n], 32);
  }
  if (kg == 0) {
#pragma unroll
    for (int n = 0; n < 8; ++n) {
      atomicAdd(&sred[n * 16 + r0], cs[n]);
      atomicAdd(&sred[128 + n * 16 + r0], cq[n]);
    }
  }
  __syncthreads();
  atomicAdd(&stats[t], sred[t]);
}

// ---------------- MFMA matmul (bf16 A) + BN column stats ----------------
__global__ __launch_bounds__(256) void k_mm1(const u16* __restrict__ A,
                                             const u16* __restrict__ Wswz,
                                             u16* __restrict__ T,
                                             float* __restrict__ stats) {
  __shared__ short wt[128 * 128];
  __shared__ float sred[256];
  int t = threadIdx.x;
  {
    const uint4* ws = (const uint4*)Wswz;
    uint4* wd = (uint4*)wt;
#pragma unroll
    for (int i = t; i < 2048; i += 256) wd[i] = ws[i];
  }
  sred[t] = 0.f;
  __syncthreads();
  int wave = t >> 6, lane = t & 63;
  int r0 = lane & 15, kg = lane >> 4;
  float cs[8], cq[8];
#pragma unroll
  for (int n = 0; n < 8; ++n) { cs[n] = 0.f; cq[n] = 0.f; }
  int strip = blockIdx.x * 4 + wave;
  if (strip < NSTRIP) {
    const u16* arow = A + (size_t)(strip * 16 + r0) * HD + kg * 8;
    short8 af[4];
#pragma unroll
    for (int kk = 0; kk < 4; ++kk) af[kk] = *(const short8*)(arow + kk * 32);
    f32x4 acc[8];
#pragma unroll
    for (int n = 0; n < 8; ++n) acc[n] = (f32x4){0.f, 0.f, 0.f, 0.f};
#pragma unroll
    for (int kk = 0; kk < 4; ++kk) {
      int kb = kk * 32 + kg * 8;
#pragma unroll
      for (int n = 0; n < 8; ++n) {
        int c = n * 16 + r0;
        short8 bf = *(const short8*)(wt + c * 128 + (kb ^ ((c & 7) << 3)));
        acc[n] = MFMA(af[kk], bf, acc[n]);
      }
    }
    u16* trow = T + (size_t)(strip * 16 + kg * 4) * HD;
#pragma unroll
    for (int n = 0; n < 8; ++n) {
#pragma unroll
      for (int j = 0; j < 4; ++j) {
        float v = acc[n][j];
        trow[(size_t)j * HD + n * 16 + r0] = (u16)f2bf(v);
        cs[n] += v;
        cq[n] = fmaf(v, v, cq[n]);
      }
    }
  }
#pragma unroll
  for (int n = 0; n < 8; ++n) {
    cs[n] += __shfl_xor(cs[n], 16); cs[n] += __shfl_xor(cs[n], 32);
    cq[n] += __shfl_xor(cq[n], 16); cq[n] += __shfl_xor(cq[n], 32);
  }
  if (kg == 0) {
#pragma unroll
    for (int n = 0; n < 8; ++n) {
      atomicAdd(&sred[n * 16 + r0], cs[n]);
      atomicAdd(&sred[128 + n * 16 + r0], cq[n]);
    }
  }
  __syncthreads();
  atomicAdd(&stats[t], sred[t]);
}

// BN-apply + relu (bf16 T in) -> bf16 h
__global__ __launch_bounds__(256) void k_bnrelu(const u16* __restrict__ T,
                                                const float* __restrict__ stats,
                                                const float* __restrict__ g,
                                                const float* __restrict__ b,
                                                u16* __restrict__ Hobf) {
  __shared__ float a_s[HD], b_s[HD];
  int t = threadIdx.x;
  if (t < HD) {
    float mean = stats[t] * (1.f / NN);
    float var = stats[HD + t] * (1.f / NN) - mean * mean;
    float a = g[t] * rsqrtf(var + LN_EPS);
    a_s[t] = a;
    b_s[t] = b[t] - mean * a;
  }
  __syncthreads();
  size_t i4 = ((size_t)blockIdx.x * 256 + t) * 4;
  if (i4 >= (size_t)NN * HD) return;
  int c = (int)(i4 & (HD - 1));
  uint2 rw = *(const uint2*)(T + i4);
  float ox = fmaxf(fmaf(a_s[c], bflo(rw.x), b_s[c]), 0.f);
  float oy = fmaxf(fmaf(a_s[c + 1], bfhi(rw.x), b_s[c + 1]), 0.f);
  float oz = fmaxf(fmaf(a_s[c + 2], bflo(rw.y), b_s[c + 2]), 0.f);
  float ow = fmaxf(fmaf(a_s[c + 3], bfhi(rw.y), b_s[c + 3]), 0.f);
  uint2 w;
  w.x = (unsigned)(u16)f2bf(ox) | ((unsigned)(u16)f2bf(oy) << 16);
  w.y = (unsigned)(u16)f2bf(oz) | ((unsigned)(u16)f2bf(ow) << 16);
  *(uint2*)(Hobf + i4) = w;
}

// ---------------- GINE aggregation: pure bf16 gather-sum + EAGG + self (8x unroll) ----------------
__global__ __launch_bounds__(256) void k_agg(const u16* __restrict__ hbf,
                                             const u16* __restrict__ eagg,
                                             const int* __restrict__ rowptr,
                                             const int* __restrict__ src_perm,
                                             const float* __restrict__ epsp, int l,
                                             u16* __restrict__ zout) {
  int t = threadIdx.x;
  int wave = t >> 6, lane = t & 63;
  int node = blockIdx.x * 4 + wave;
  if (node >= NN) return;
  int p0 = rowptr[node], p1 = rowptr[node + 1];
  float ax = 0.f, ay = 0.f;
  int p = p0;
  for (; p + 7 < p1; p += 8) {
    int s[8];
#pragma unroll
    for (int i = 0; i < 8; ++i) s[i] = src_perm[p + i];
    unsigned h[8];
#pragma unroll
    for (int i = 0; i < 8; ++i)
      h[i] = *(const unsigned*)(hbf + (size_t)s[i] * HD + 2 * lane);
#pragma unroll
    for (int i = 0; i < 8; ++i) {
      ax += bflo(h[i]);
      ay += bfhi(h[i]);
    }
  }
  for (; p + 3 < p1; p += 4) {
    int s0 = src_perm[p], s1 = src_perm[p + 1], s2 = src_perm[p + 2],
        s3 = src_perm[p + 3];
    unsigned h0 = *(const unsigned*)(hbf + (size_t)s0 * HD + 2 * lane);
    unsigned h1 = *(const unsigned*)(hbf + (size_t)s1 * HD + 2 * lane);
    unsigned h2 = *(const unsigned*)(hbf + (size_t)s2 * HD + 2 * lane);
    unsigned h3 = *(const unsigned*)(hbf + (size_t)s3 * HD + 2 * lane);
    ax += (bflo(h0) + bflo(h1)) + (bflo(h2) + bflo(h3));
    ay += (bfhi(h0) + bfhi(h1)) + (bfhi(h2) + bfhi(h3));
  }
  for (; p < p1; ++p) {
    int s0 = src_perm[p];
    unsigned h0 = *(const unsigned*)(hbf + (size_t)s0 * HD + 2 * lane);
    ax += bflo(h0);
    ay += bfhi(h0);
  }
  float e1 = 1.f + epsp[l];
  unsigned hs = *(const unsigned*)(hbf + (size_t)node * HD + 2 * lane);
  unsigned eg = *(const unsigned*)(eagg + (size_t)node * HD + 2 * lane);
  float zx = fmaf(e1, bflo(hs), ax + bflo(eg));
  float zy = fmaf(e1, bfhi(hs), ay + bfhi(eg));
  unsigned zo = (unsigned)(u16)f2bf(zx) | ((unsigned)(u16)f2bf(zy) << 16);
  *(unsigned*)(zout + (size_t)node * HD + 2 * lane) = zo;
}

// ---------------- BN-apply + MFMA matmul2 + LN + residual (all bf16) ----------------
__global__ __launch_bounds__(256) void k_mm2(const u16* __restrict__ T,
                                             const float* __restrict__ stats,
                                             const float* __restrict__ bng,
                                             const float* __restrict__ bnb,
                                             const u16* __restrict__ Wswz,
                                             const float* __restrict__ b2,
                                             const float* __restrict__ lng,
                                             const float* __restrict__ lnb,
                                             const u16* __restrict__ hprevb,
                                             u16* __restrict__ houtbf) {
  __shared__ short wt[128 * 128];
  __shared__ float abl[256];
  int t = threadIdx.x;
  {
    const uint4* ws = (const uint4*)Wswz;
    uint4* wd = (uint4*)wt;
#pragma unroll
    for (int i = t; i < 2048; i += 256) wd[i] = ws[i];
  }
  if (t < 128) {
    float mean = stats[t] * (1.f / NN);
    float var = stats[HD + t] * (1.f / NN) - mean * mean;
    float a = bng[t] * rsqrtf(var + LN_EPS);
    abl[t] = a;
    abl[128 + t] = bnb[t] - mean * a;
  }
  __syncthreads();
  int wave = t >> 6, lane = t & 63;
  int r0 = lane & 15, kg = lane >> 4;
  float bc[8], gc[8], bbc[8];
#pragma unroll
  for (int n = 0; n < 8; ++n) {
    int c = n * 16 + r0;
    bc[n] = b2[c];
    gc[n] = lng[c];
    bbc[n] = lnb[c];
  }
  int strip = blockIdx.x * 4 + wave;
  if (strip < NSTRIP) {
    const u16* trow = T + (size_t)(strip * 16 + r0) * HD + kg * 8;
    short8 af[4];
#pragma unroll
    for (int kk = 0; kk < 4; ++kk) {
      int kb = kk * 32 + kg * 8;
      uint4 rw = *(const uint4*)(trow + kk * 32);
      float f0 = bflo(rw.x), f1 = bfhi(rw.x), f2 = bflo(rw.y), f3 = bfhi(rw.y);
      float f4 = bflo(rw.z), f5 = bfhi(rw.z), f6 = bflo(rw.w), f7 = bfhi(rw.w);
      short8 v;
      v[0] = f2bf(fmaxf(fmaf(abl[kb + 0], f0, abl[128 + kb + 0]), 0.f));
      v[1] = f2bf(fmaxf(fmaf(abl[kb + 1], f1, abl[128 + kb + 1]), 0.f));
      v[2] = f2bf(fmaxf(fmaf(abl[kb + 2], f2, abl[128 + kb + 2]), 0.f));
      v[3] = f2bf(fmaxf(fmaf(abl[kb + 3], f3, abl[128 + kb + 3]), 0.f));
      v[4] = f2bf(fmaxf(fmaf(abl[kb + 4], f4, abl[128 + kb + 4]), 0.f));
      v[5] = f2bf(fmaxf(fmaf(abl[kb + 5], f5, abl[128 + kb + 5]), 0.f));
      v[6] = f2bf(fmaxf(fmaf(abl[kb + 6], f6, abl[128 + kb + 6]), 0.f));
      v[7] = f2bf(fmaxf(fmaf(abl[kb + 7], f7, abl[128 + kb + 7]), 0.f));
      af[kk] = v;
    }
    f32x4 acc[8];
#pragma unroll
    for (int n = 0; n < 8; ++n) acc[n] = (f32x4){0.f, 0.f, 0.f, 0.f};
#pragma unroll
    for (int kk = 0; kk < 4; ++kk) {
      int kb = kk * 32 + kg * 8;
#pragma unroll
      for (int n = 0; n < 8; ++n) {
        int c = n * 16 + r0;
        short8 bf = *(const short8*)(wt + c * 128 + (kb ^ ((c & 7) << 3)));
        acc[n] = MFMA(af[kk], bf, acc[n]);
      }
    }
#pragma unroll
    for (int j = 0; j < 4; ++j) {
      float s = 0.f, sq = 0.f;
#pragma unroll
      for (int n = 0; n < 8; ++n) {
        float v = acc[n][j] + bc[n];
        acc[n][j] = v;
        s += v;
        sq = fmaf(v, v, sq);
      }
      s += __shfl_xor(s, 1); sq += __shfl_xor(sq, 1);
      s += __shfl_xor(s, 2); sq += __shfl_xor(sq, 2);
      s += __shfl_xor(s, 4); sq += __shfl_xor(sq, 4);
      s += __shfl_xor(s, 8); sq += __shfl_xor(sq, 8);
      float mu = s * (1.f / HD);
      float var = sq * (1.f / HD) - mu * mu;
      float rs = rsqrtf(var + LN_EPS);
      size_t rb = (size_t)(strip * 16 + kg * 4 + j) * HD;
      const u16* hp = hprevb + rb;
      u16* hob = houtbf + rb;
#pragma unroll
      for (int n = 0; n < 8; ++n) {
        int c = n * 16 + r0;
        float o = fmaxf(fmaf(gc[n], (acc[n][j] - mu) * rs, bbc[n]) + bf1(hp[c]), 0.f);
        hob[c] = (u16)f2bf(o);
      }
    }
  }
}

// ---------------- JK attention (bf16 in, bf16 out; combine from registers) ----------------
__global__ __launch_bounds__(256) void k_jk(const u16* __restrict__ hb1,
                                            const u16* __restrict__ hb2,
                                            const u16* __restrict__ hb3,
                                            const u16* __restrict__ Wswz,
                                            const float* __restrict__ b1,
                                            const float* __restrict__ w2,
                                            const float* __restrict__ b2,
                                            u16* __restrict__ xn) {
  __shared__ short wt[64 * 128];
  __shared__ float elds[4][3][16];
  int t = threadIdx.x;
  {
    const uint4* ws = (const uint4*)Wswz;
    uint4* wd = (uint4*)wt;
#pragma unroll
    for (int i = t; i < 1024; i += 256) wd[i] = ws[i];
  }
  __syncthreads();
  int wave = t >> 6, lane = t & 63;
  int r0 = lane & 15, kg = lane >> 4;
  float jb1[4], w2c[4];
#pragma unroll
  for (int n = 0; n < 4; ++n) {
    jb1[n] = b1[n * 16 + r0];
    w2c[n] = w2[n * 16 + r0];
  }
  float jb2 = b2[0];
  const u16* hbs[3] = {hb1, hb2, hb3};
  int strip = blockIdx.x * 4 + wave;
  if (strip >= NSTRIP) return;
  {
    f32x4 acc[3][4];
    short8 af3[3][4];
#pragma unroll
    for (int l = 0; l < 3; ++l) {
      const u16* arow = hbs[l] + (size_t)(strip * 16 + r0) * HD + kg * 8;
#pragma unroll
      for (int kk = 0; kk < 4; ++kk) af3[l][kk] = *(const short8*)(arow + kk * 32);
#pragma unroll
      for (int n = 0; n < 4; ++n) acc[l][n] = (f32x4){0.f, 0.f, 0.f, 0.f};
#pragma unroll
      for (int kk = 0; kk < 4; ++kk) {
        int kb = kk * 32 + kg * 8;
#pragma unroll
        for (int n = 0; n < 4; ++n) {
          int c = n * 16 + r0;
          short8 bf = *(const short8*)(wt + c * 128 + (kb ^ ((c & 7) << 3)));
          acc[l][n] = MFMA(af3[l][kk], bf, acc[l][n]);
        }
      }
    }
#pragma unroll
    for (int j = 0; j < 4; ++j) {
      float sc[3];
#pragma unroll
      for (int l = 0; l < 3; ++l) {
        float p = 0.f;
#pragma unroll
        for (int n = 0; n < 4; ++n)
          p = fmaf(fmaxf(acc[l][n][j] + jb1[n], 0.f), w2c[n], p);
        p += __shfl_xor(p, 1);
        p += __shfl_xor(p, 2);
        p += __shfl_xor(p, 4);
        p += __shfl_xor(p, 8);
        sc[l] = p + jb2;
      }
      float m = fmaxf(sc[0], fmaxf(sc[1], sc[2]));
      float e0 = expf(sc[0] - m), e1 = expf(sc[1] - m), e2 = expf(sc[2] - m);
      float inv = 1.f / (e0 + e1 + e2);
      if (r0 == j) {
        elds[wave][0][kg * 4 + j] = e0 * inv;
        elds[wave][1][kg * 4 + j] = e1 * inv;
        elds[wave][2][kg * 4 + j] = e2 * inv;
      }
    }
    float e0r = elds[wave][0][r0];
    float e1r = elds[wave][1][r0];
    float e2r = elds[wave][2][r0];
    size_t rowb = (size_t)(strip * 16 + r0) * HD + kg * 8;
#pragma unroll
    for (int kk = 0; kk < 4; ++kk) {
      uint4 ow;
      unsigned owp[4];
#pragma unroll
      for (int h = 0; h < 4; ++h) {
        float v0 = e0r * bf1((u16)af3[0][kk][2 * h]) + e1r * bf1((u16)af3[1][kk][2 * h]) +
                   e2r * bf1((u16)af3[2][kk][2 * h]);
        float v1 = e0r * bf1((u16)af3[0][kk][2 * h + 1]) +
                   e1r * bf1((u16)af3[1][kk][2 * h + 1]) +
                   e2r * bf1((u16)af3[2][kk][2 * h + 1]);
        owp[h] = (unsigned)(u16)f2bf(v0) | ((unsigned)(u16)f2bf(v1) << 16);
      }
      ow.x = owp[0]; ow.y = owp[1]; ow.z = owp[2]; ow.w = owp[3];
      *(uint4*)(xn + rowb + kk * 32) = ow;
    }
  }
}

// ---------------- graph pooling stage 1 ----------------
__device__ __forceinline__ void seg_bounds(const int* batch, int g, int& start, int& end) {
  int lo = 0, hi = NN;
  while (lo < hi) {
    int mid = (lo + hi) >> 1;
    if (batch[mid] < g) lo = mid + 1; else hi = mid;
  }
  start = lo;
  lo = start; hi = NN;
  while (lo < hi) {
    int mid = (lo + hi) >> 1;
    if (batch[mid] < g + 1) lo = mid + 1; else hi = mid;
  }
  end = lo;
}

__global__ __launch_bounds__(128) void k_pool1(const u16* __restrict__ xn,
                                               const int* __restrict__ batch,
                                               float* __restrict__ partial) {
  int g = blockIdx.x >> 5, ch = blockIdx.x & (PCH - 1), c = threadIdx.x;
  int start, end;
  seg_bounds(batch, g, start, end);
  int len = end - start;
  int n0 = start + (int)((long long)len * ch / PCH);
  int n1 = start + (int)((long long)len * (ch + 1) / PCH);
  float sum = 0.f, m = -INFINITY;
  for (int n = n0; n < n1; ++n) {
    float v = bf1(xn[(size_t)n * HD + c]);
    sum += v;
    m = fmaxf(m, v);
  }
  partial[((size_t)(g * PCH + ch) * 2 + 0) * HD + c] = sum;
  partial[((size_t)(g * PCH + ch) * 2 + 1) * HD + c] = m;
}

// ---------------- fused tail: pool2 + te-LN + concat-LN + classifier matmul ----------------
__global__ __launch_bounds__(576) void k_tail(
    const float* __restrict__ partial, const int* __restrict__ batch,
    const float* __restrict__ teacc, const float* __restrict__ tf_b,
    const float* __restrict__ tf_lng, const float* __restrict__ tf_lnb,
    const float* __restrict__ gfeat, const float* __restrict__ gf_w,
    const float* __restrict__ gf_b, const float* __restrict__ pre_lng,
    const float* __restrict__ pre_lnb, const float* __restrict__ cls_w1,
    const float* __restrict__ cls_b1, float* __restrict__ cw) {
  int g = blockIdx.x, t = threadIdx.x;
  __shared__ float ssum[128], smx[128], tearr[128], gfarr[32], rowb[CDIM];
  __shared__ float wsum[9], wsq[9], tred[4];
  __shared__ float cnt_s, mu_s, rs_s, tmu_s, trs_s;
  if (t < 128) {
    float sum = 0.f, m = -INFINITY;
    for (int ch = 0; ch < PCH; ++ch) {
      sum += partial[((size_t)(g * PCH + ch) * 2 + 0) * HD + t];
      m = fmaxf(m, partial[((size_t)(g * PCH + ch) * 2 + 1) * HD + t]);
    }
    ssum[t] = sum;
    smx[t] = m;
  } else if (t < 256) {
    int c = t - 128;
    tearr[c] = teacc[g * HD + c] + tf_b[c];
  } else if (t < 288) {
    int c = t - 256;
    float a = gf_b[c];
#pragma unroll
    for (int k = 0; k < NSD; ++k) a = fmaf(gfeat[g * NSD + k], gf_w[k * 32 + c], a);
    gfarr[c] = a;
  } else if (t == 544) {
    int s0, e0;
    seg_bounds(batch, g, s0, e0);
    cnt_s = fmaxf((float)(e0 - s0), 1.f);
  }
  __syncthreads();
  // te layer-norm over tearr[128] (waves 0-1)
  {
    int wave = t >> 6, lane = t & 63;
    if (t < 128) {
      float v = tearr[t];
      float sv = v, sq = v * v;
#pragma unroll
      for (int o = 32; o; o >>= 1) {
        sv += __shfl_down(sv, o);
        sq += __shfl_down(sq, o);
      }
      if (lane == 0) {
        tred[wave] = sv;
        tred[2 + wave] = sq;
      }
    }
  }
  __syncthreads();
  if (t == 0) {
    float tot = tred[0] + tred[1], tot2 = tred[2] + tred[3];
    float mu = tot * (1.f / HD);
    tmu_s = mu;
    trs_s = rsqrtf(tot2 * (1.f / HD) - mu * mu + LN_EPS);
  }
  __syncthreads();
  if (t < 128)
    tearr[t] = fmaxf(fmaf(tf_lng[t], (tearr[t] - tmu_s) * trs_s, tf_lnb[t]), 0.f);
  __syncthreads();
  // concat + pre-LN over 544
  float v = 0.f;
  if (t < 128) v = ssum[t] / cnt_s;
  else if (t < 256) v = smx[t - 128];
  else if (t < 384) v = ssum[t - 256];
  else if (t < 416) v = gfarr[t - 384];
  else if (t < CDIM) v = tearr[t - 416];
  {
    int wave = t >> 6, lane = t & 63;
    float sv = (t < CDIM) ? v : 0.f;
    float ss = sv, sq = sv * sv;
#pragma unroll
    for (int o = 32; o; o >>= 1) {
      ss += __shfl_down(ss, o);
      sq += __shfl_down(sq, o);
    }
    if (lane == 0) {
      wsum[wave] = ss;
      wsq[wave] = sq;
    }
  }
  __syncthreads();
  if (t == 0) {
    float a = 0.f, bq = 0.f;
    for (int i = 0; i < 9; ++i) {
      a += wsum[i];
      bq += wsq[i];
    }
    float mu = a * (1.f / CDIM);
    mu_s = mu;
    rs_s = rsqrtf(bq * (1.f / CDIM) - mu * mu + LN_EPS);
  }
  __syncthreads();
  if (t < CDIM) rowb[t] = fmaf(pre_lng[t], (v - mu_s) * rs_s, pre_lnb[t]);
  __syncthreads();
  if (t < 128) {
    float acc = cls_b1[t];
    for (int k = 0; k < CDIM; ++k) acc = fmaf(rowb[k], cls_w1[(size_t)k * HD + t], acc);
    cw[g * HD + t] = acc;
  }
}

// ---------------- final BN + logits ----------------
__global__ __launch_bounds__(128) void k_head(const float* __restrict__ cw,
                                              const float* __restrict__ bng,
                                              const float* __restrict__ bnb,
                                              const float* __restrict__ w2,
                                              const float* __restrict__ b2,
                                              float* __restrict__ out) {
  __shared__ float act[HD * NG];
  int c = threadIdx.x;
  float sum = 0.f, ssq = 0.f;
  float vals[NG];
#pragma unroll
  for (int g = 0; g < NG; ++g) {
    float v = cw[g * HD + c];
    vals[g] = v;
    sum += v;
    ssq = fmaf(v, v, ssq);
  }
  float mu = sum * (1.f / NG);
  float var = ssq * (1.f / NG) - mu * mu;
  float a = bng[c] * rsqrtf(var + LN_EPS);
  float bb = bnb[c] - mu * a;
#pragma unroll
  for (int g = 0; g < NG; ++g) act[c * NG + g] = fmaxf(fmaf(a, vals[g], bb), 0.f);
  __syncthreads();
  if (c < NG) {
    float acc = b2[0];
    for (int k = 0; k < HD; ++k) acc = fmaf(act[k * NG + c], w2[k], acc);
    out[c] = acc;
  }
}

extern "C" void kernel_launch(void* const* d_in, const int* in_sizes, int n_in,
                              void* d_out, int out_size, void* d_ws, size_t ws_size,
                              hipStream_t stream) {
  (void)in_sizes; (void)n_in; (void)out_size; (void)ws_size;
  const float* x = (const float*)d_in[0];
  const float* edge_attr = (const float*)d_in[1];
  const float* gfeat = (const float*)d_in[2];
  const float* tfidf = (const float*)d_in[3];
  const float* w_in = (const float*)d_in[4];
  const float* g_in = (const float*)d_in[6];
  const float* be_in = (const float*)d_in[7];
  const float* w_e = (const float*)d_in[8];
  const float* b_e = (const float*)d_in[9];
  const float* conv_w1 = (const float*)d_in[10];
  const float* conv_bng = (const float*)d_in[12];
  const float* conv_bnb = (const float*)d_in[13];
  const float* conv_w2 = (const float*)d_in[14];
  const float* conv_b2 = (const float*)d_in[15];
  const float* conv_eps = (const float*)d_in[16];
  const float* conv_lng = (const float*)d_in[17];
  const float* conv_lnb = (const float*)d_in[18];
  const float* jk_w1 = (const float*)d_in[19];
  const float* jk_b1 = (const float*)d_in[20];
  const float* jk_w2 = (const float*)d_in[21];
  const float* jk_b2 = (const float*)d_in[22];
  const float* gf_w = (const float*)d_in[23];
  const float* gf_b = (const float*)d_in[24];
  const float* tf_w = (const float*)d_in[25];
  const float* tf_b = (const float*)d_in[26];
  const float* tf_lng = (const float*)d_in[27];
  const float* tf_lnb = (const float*)d_in[28];
  const float* pre_lng = (const float*)d_in[29];
  const float* pre_lnb = (const float*)d_in[30];
  const float* cls_w1 = (const float*)d_in[31];
  const float* cls_b1 = (const float*)d_in[32];
  const float* cls_bng = (const float*)d_in[33];
  const float* cls_bnb = (const float*)d_in[34];
  const float* cls_w2 = (const float*)d_in[35];
  const float* cls_b2 = (const float*)d_in[36];
  const int* edge_index = (const int*)d_in[37];
  const int* batch = (const int*)d_in[38];
  const int* srcp = edge_index;
  const int* dstp = edge_index + NE;
  float* out = (float*)d_out;

  char* ws = (char*)d_ws;
  size_t off = 0;
  auto alloc = [&](size_t bytes) -> void* {
    void* p = ws + off;
    off += (bytes + 255) & ~(size_t)255;
    return p;
  };
  int* cnt = (int*)alloc((size_t)NN * 4);
  int* rowptr = (int*)alloc((size_t)(NN + 1) * 4);
  int* nextp = (int*)alloc((size_t)NN * 4);
  int* tileSum = (int*)alloc(64 * 4);
  int* tileOff = (int*)alloc(64 * 4);
  int* src_perm = (int*)alloc((size_t)NE * 4);
  u16* attr_bf = (u16*)alloc((size_t)NE * DE * 2);
  u16* wpre = (u16*)alloc((size_t)WPRE_TOTAL * 2);
  u16* eaggb = (u16*)alloc((size_t)NN * HD * 2);
  u16* zb = (u16*)alloc((size_t)NN * HD * 2);
  u16* tbuf = (u16*)alloc((size_t)NN * HD * 2);
  u16* hbB[4];
  for (int i = 0; i < 4; ++i) hbB[i] = (u16*)alloc((size_t)NN * HD * 2);
  float* statsAll = (float*)alloc(4 * 256 * 4);
  float* partial = (float*)alloc((size_t)NG * PCH * 2 * HD * 4);
  float* teacc = (float*)alloc((size_t)NG * HD * 4);
  float* cwbuf = (float*)alloc((size_t)NG * HD * 4);
  u16* xn = zb;  // zb dead after last k_mm1

  hipMemsetAsync(cnt, 0, (size_t)NN * 4, stream);
  hipMemsetAsync(statsAll, 0, 4 * 256 * 4, stream);
  hipMemsetAsync(teacc, 0, (size_t)NG * HD * 4, stream);

  k_prep<<<CNT_BLOCKS + WCVT_BLOCKS, 256, 0, stream>>>(dstp, cnt, w_in, conv_w1, conv_w2,
                                                       jk_w1, wpre);
  k_te1<<<TE_BLOCKS, 256, 0, stream>>>(tfidf, tf_w, teacc);
  k_scan1<<<NTILES, 256, 0, stream>>>(cnt, rowptr, tileSum);
  k_scan2<<<1, 64, 0, stream>>>(tileSum, tileOff, rowptr);
  k_scan3<<<(NN + 255) / 256, 256, 0, stream>>>(tileOff, rowptr, nextp);
  k_fill<<<(NE / 2 + 255) / 256, 256, 0, stream>>>(srcp, dstp, edge_attr, nextp,
                                                   src_perm, attr_bf);
  k_eagg<<<(NN + 3) / 4, 256, 0, stream>>>(rowptr, attr_bf, w_e, b_e, eaggb);

  k_mm1f<DIN><<<MM_GRID, 256, 0, stream>>>(x, wpre + OFF_IN, tbuf, statsAll);
  k_bnrelu<<<(NN * HD / 4 + 255) / 256, 256, 0, stream>>>(tbuf, statsAll, g_in, be_in,
                                                          hbB[0]);

  for (int l = 0; l < NL; ++l) {
    k_agg<<<(NN + 3) / 4, 256, 0, stream>>>(hbB[l], eaggb, rowptr, src_perm, conv_eps, l,
                                            zb);
    k_mm1<<<MM_GRID, 256, 0, stream>>>(zb, wpre + OFF_W1 + l * 16384, tbuf,
                                       statsAll + (1 + l) * 256);
    k_mm2<<<MM_GRID, 256, 0, stream>>>(tbuf, statsAll + (1 + l) * 256, conv_bng + l * HD,
                                       conv_bnb + l * HD, wpre + OFF_W2 + l * 16384,
                                       conv_b2 + l * HD, conv_lng + l * HD,
                                       conv_lnb + l * HD, hbB[l], hbB[l + 1]);
  }

  k_jk<<<MM_GRID, 256, 0, stream>>>(hbB[1], hbB[2], hbB[3], wpre + OFF_JK, jk_b1, jk_w2,
                                    jk_b2, xn);
  k_pool1<<<NG * PCH, 128, 0, stream>>>(xn, batch, partial);
  k_tail<<<NG, 576, 0, stream>>>(partial, batch, teacc, tf_b, tf_lng, tf_lnb, gfeat,
                                 gf_w, gf_b, pre_lng, pre_lnb, cls_w1, cls_b1, cwbuf);
  k_head<<<1, 128, 0, stream>>>(cwbuf, cls_bng, cls_bnb, cls_w2, cls_b2, out);
}

// Round 13
// 413.210 us; speedup vs baseline: 1.0331x; 1.0331x over previous
//
#include <hip/hip_runtime.h>
#include <hip/hip_bf16.h>
#include <math.h>

#define NN 50000
#define NE 500000
#define NG 64
#define DIN 64
#define DE 8
#define HD 128
#define TFD 2000
#define NSD 10
#define NL 3
#define CDIM 544
#define LN_EPS 1e-5f
#define NSTRIP 3125  // 50000 / 16
#define PCH 32
#define NTILES 49    // ceil(50000/1024)
#define MM_GRID 782  // 782*4 = 3128 waves >= 3125 strips

// pre-swizzled bf16 weight buffer offsets (in u16 elements)
#define OFF_IN 0
#define OFF_W1 8192
#define OFF_W2 57344
#define OFF_JK 106496
#define WPRE_TOTAL 114688
#define CNT_BLOCKS 977   // ceil(NE/2/256) for k_prep count half (2 edges/thread)
#define WCVT_BLOCKS 448  // ceil(WPRE_TOTAL/256)

typedef float f32x4 __attribute__((ext_vector_type(4)));
typedef short short8 __attribute__((ext_vector_type(8)));
typedef __bf16 bf16x8_t __attribute__((ext_vector_type(8)));
typedef unsigned short u16;

__device__ __forceinline__ short f2bf(float f) {
  unsigned u = __builtin_bit_cast(unsigned, f);
  u += 0x7fffu + ((u >> 16) & 1u);
  return (short)(u >> 16);
}

__device__ __forceinline__ float bflo(unsigned v) {
  return __builtin_bit_cast(float, v << 16);
}
__device__ __forceinline__ float bfhi(unsigned v) {
  return __builtin_bit_cast(float, v & 0xffff0000u);
}
__device__ __forceinline__ float bf1(u16 v) {
  return __builtin_bit_cast(float, (unsigned)v << 16);
}

__device__ __forceinline__ f32x4 MFMA(short8 a, short8 b, f32x4 c) {
  return __builtin_amdgcn_mfma_f32_16x16x32_bf16(
      __builtin_bit_cast(bf16x8_t, a), __builtin_bit_cast(bf16x8_t, b), c, 0, 0, 0);
}

// ---------------- fused: edge count (2 edges/thread) + weight pre-convert ----------------
__global__ void k_prep(const int* __restrict__ dst, int* __restrict__ cnt,
                       const float* __restrict__ w_in, const float* __restrict__ conv_w1,
                       const float* __restrict__ conv_w2, const float* __restrict__ jk_w1,
                       u16* __restrict__ wpre) {
  int b = blockIdx.x;
  if (b < CNT_BLOCKS) {
    int e = (b * 256 + threadIdx.x) * 2;
    if (e < NE) atomicAdd(&cnt[dst[e]], 1);
    if (e + 1 < NE) atomicAdd(&cnt[dst[e + 1]], 1);
    return;
  }
  int i = (b - CNT_BLOCKS) * 256 + threadIdx.x;
  if (i >= WPRE_TOTAL) return;
  if (i < OFF_W1) {
    int c = i & 127, k = i >> 7;  // k 0..63
    wpre[OFF_IN + c * 64 + (k ^ ((c & 7) << 3))] = (u16)f2bf(w_in[(size_t)k * 128 + c]);
  } else if (i < OFF_W2) {
    int i2 = i - OFF_W1;
    int l = i2 >> 14, r = i2 & 16383;
    int c = r & 127, k = r >> 7;
    wpre[OFF_W1 + l * 16384 + c * 128 + (k ^ ((c & 7) << 3))] =
        (u16)f2bf(conv_w1[(size_t)l * 16384 + k * 128 + c]);
  } else if (i < OFF_JK) {
    int i2 = i - OFF_W2;
    int l = i2 >> 14, r = i2 & 16383;
    int c = r & 127, k = r >> 7;
    wpre[OFF_W2 + l * 16384 + c * 128 + (k ^ ((c & 7) << 3))] =
        (u16)f2bf(conv_w2[(size_t)l * 16384 + k * 128 + c]);
  } else {
    int i2 = i - OFF_JK;
    int c = i2 & 63, k = i2 >> 6;  // k 0..127
    wpre[OFF_JK + c * 128 + (k ^ ((c & 7) << 3))] = (u16)f2bf(jk_w1[(size_t)k * 64 + c]);
  }
}

// ---------------- tfidf matmul: teacc[g][c] = tfidf[g] @ w[:,c] (4-way K split/block) ----------------
__global__ __launch_bounds__(512) void k_te2(const float* __restrict__ tfidf,
                                             const float* __restrict__ w,
                                             float* __restrict__ teacc) {
  int gi = blockIdx.x, t = threadIdx.x;
  int c = t & 127, seg = t >> 7;
  const float* trow = tfidf + (size_t)gi * TFD;
  float acc = 0.f;
  for (int k = seg * 500; k < (seg + 1) * 500; ++k)
    acc = fmaf(trow[k], w[(size_t)k * HD + c], acc);
  __shared__ float pacc[4][HD];
  pacc[seg][c] = acc;
  __syncthreads();
  if (t < HD) teacc[gi * HD + t] = pacc[0][t] + pacc[1][t] + pacc[2][t] + pacc[3][t];
}

// ---------------- CSR scan ----------------
__global__ __launch_bounds__(256) void k_scan1(const int* __restrict__ cnt,
                                               int* __restrict__ rowptr,
                                               int* __restrict__ tileSum) {
  __shared__ int wsum[4];
  int tile = blockIdx.x;
  int base = tile * 1024;
  int t = threadIdx.x, lane = t & 63, wave = t >> 6;
  int idx = base + t * 4;
  int4 v = make_int4(0, 0, 0, 0);
  if (idx + 3 < NN) {
    v = *(const int4*)(cnt + idx);
  } else if (idx < NN) {
    v.x = cnt[idx];
    v.y = (idx + 1 < NN) ? cnt[idx + 1] : 0;
    v.z = (idx + 2 < NN) ? cnt[idx + 2] : 0;
    v.w = (idx + 3 < NN) ? cnt[idx + 3] : 0;
  }
  int s = v.x + v.y + v.z + v.w;
  int incl = s;
#pragma unroll
  for (int o = 1; o < 64; o <<= 1) {
    int n = __shfl_up(incl, o);
    if (lane >= o) incl += n;
  }
  if (lane == 63) wsum[wave] = incl;
  __syncthreads();
  int wbase = 0;
  for (int w = 0; w < wave; ++w) wbase += wsum[w];
  int ex = wbase + incl - s;
  if (idx < NN) rowptr[idx] = ex;
  if (idx + 1 < NN) rowptr[idx + 1] = ex + v.x;
  if (idx + 2 < NN) rowptr[idx + 2] = ex + v.x + v.y;
  if (idx + 3 < NN) rowptr[idx + 3] = ex + v.x + v.y + v.z;
  if (t == 255) tileSum[tile] = wbase + incl;
}

__global__ __launch_bounds__(64) void k_scan2(const int* __restrict__ tileSum,
                                              int* __restrict__ tileOff,
                                              int* __restrict__ rowptr) {
  int t = threadIdx.x;
  int v = (t < NTILES) ? tileSum[t] : 0;
  int incl = v;
#pragma unroll
  for (int o = 1; o < 64; o <<= 1) {
    int n = __shfl_up(incl, o);
    if (t >= o) incl += n;
  }
  if (t < NTILES) tileOff[t] = incl - v;
  if (t == 63) rowptr[NN] = incl;
}

__global__ void k_scan3(const int* __restrict__ tileOff, int* __restrict__ rowptr,
                        int* __restrict__ nextp) {
  int i = blockIdx.x * 256 + threadIdx.x;
  if (i < NN) {
    int v = rowptr[i] + tileOff[i >> 10];
    rowptr[i] = v;
    nextp[i] = v;
  }
}

// fill: counting-sort by dst -> src_perm + CSR-ordered bf16 edge attrs (2 edges/thread)
__global__ void k_fill(const int* __restrict__ src, const int* __restrict__ dst,
                       const float* __restrict__ eattr, int* __restrict__ nextp,
                       int* __restrict__ src_perm, u16* __restrict__ attr_bf) {
  int e = (blockIdx.x * 256 + threadIdx.x) * 2;
  if (e >= NE) return;
  int d0 = dst[e];
  int s0 = src[e];
  const float4* a0p = (const float4*)(eattr + (size_t)e * DE);
  float4 a00 = a0p[0], a01 = a0p[1];
  bool has1 = (e + 1 < NE);
  int d1 = 0, s1 = 0;
  float4 a10, a11;
  if (has1) {
    d1 = dst[e + 1];
    s1 = src[e + 1];
    const float4* a1p = (const float4*)(eattr + (size_t)(e + 1) * DE);
    a10 = a1p[0];
    a11 = a1p[1];
  }
  int pos0 = atomicAdd(&nextp[d0], 1);
  int pos1 = has1 ? atomicAdd(&nextp[d1], 1) : 0;
  src_perm[pos0] = s0;
  uint4 w0;
  w0.x = (unsigned)(u16)f2bf(a00.x) | ((unsigned)(u16)f2bf(a00.y) << 16);
  w0.y = (unsigned)(u16)f2bf(a00.z) | ((unsigned)(u16)f2bf(a00.w) << 16);
  w0.z = (unsigned)(u16)f2bf(a01.x) | ((unsigned)(u16)f2bf(a01.y) << 16);
  w0.w = (unsigned)(u16)f2bf(a01.z) | ((unsigned)(u16)f2bf(a01.w) << 16);
  *(uint4*)(attr_bf + (size_t)pos0 * DE) = w0;
  if (has1) {
    src_perm[pos1] = s1;
    uint4 w1;
    w1.x = (unsigned)(u16)f2bf(a10.x) | ((unsigned)(u16)f2bf(a10.y) << 16);
    w1.y = (unsigned)(u16)f2bf(a10.z) | ((unsigned)(u16)f2bf(a10.w) << 16);
    w1.z = (unsigned)(u16)f2bf(a11.x) | ((unsigned)(u16)f2bf(a11.y) << 16);
    w1.w = (unsigned)(u16)f2bf(a11.z) | ((unsigned)(u16)f2bf(a11.w) << 16);
    *(uint4*)(attr_bf + (size_t)pos1 * DE) = w1;
  }
}

// EAGG[node] = sum over incoming edges of relu(attr @ w_e + b_e)
__device__ __forceinline__ void eagg_body(uint4 aw, const float2* wv, float2 be2,
                                          float& ax, float& ay) {
  float a[8] = {bflo(aw.x), bfhi(aw.x), bflo(aw.y), bfhi(aw.y),
                bflo(aw.z), bfhi(aw.z), bflo(aw.w), bfhi(aw.w)};
  float ex = be2.x, ey = be2.y;
#pragma unroll
  for (int k = 0; k < 8; ++k) {
    ex = fmaf(a[k], wv[k].x, ex);
    ey = fmaf(a[k], wv[k].y, ey);
  }
  ax += fmaxf(ex, 0.f);
  ay += fmaxf(ey, 0.f);
}

__global__ __launch_bounds__(256) void k_eagg(const int* __restrict__ rowptr,
                                              const u16* __restrict__ attr_bf,
                                              const float* __restrict__ we,
                                              const float* __restrict__ be,
                                              u16* __restrict__ eagg) {
  int t = threadIdx.x;
  int wave = t >> 6, lane = t & 63;
  float2 wv[8];
#pragma unroll
  for (int k = 0; k < 8; ++k) wv[k] = ((const float2*)(we + k * HD))[lane];
  float2 be2 = ((const float2*)be)[lane];
  int node = blockIdx.x * 4 + wave;
  if (node >= NN) return;
  int p0 = rowptr[node], p1 = rowptr[node + 1];
  float ax = 0.f, ay = 0.f;
  int p = p0;
  for (; p + 3 < p1; p += 4) {
    uint4 w0 = *(const uint4*)(attr_bf + (size_t)p * DE);
    uint4 w1 = *(const uint4*)(attr_bf + (size_t)(p + 1) * DE);
    uint4 w2 = *(const uint4*)(attr_bf + (size_t)(p + 2) * DE);
    uint4 w3 = *(const uint4*)(attr_bf + (size_t)(p + 3) * DE);
    eagg_body(w0, wv, be2, ax, ay);
    eagg_body(w1, wv, be2, ax, ay);
    eagg_body(w2, wv, be2, ax, ay);
    eagg_body(w3, wv, be2, ax, ay);
  }
  for (; p < p1; ++p) {
    uint4 w0 = *(const uint4*)(attr_bf + (size_t)p * DE);
    eagg_body(w0, wv, be2, ax, ay);
  }
  unsigned w = (unsigned)(u16)f2bf(ax) | ((unsigned)(u16)f2bf(ay) << 16);
  *(unsigned*)(eagg + (size_t)node * HD + 2 * lane) = w;
}

// ---------------- MFMA matmul (f32 A, input layer) + BN column stats ----------------
template <int KD>
__global__ __launch_bounds__(256) void k_mm1f(const float* __restrict__ A,
                                              const u16* __restrict__ Wswz,
                                              u16* __restrict__ T,
                                              float* __restrict__ stats) {
  constexpr int KCH = KD / 32;
  __shared__ short wt[128 * KD];
  __shared__ float sred[256];
  int t = threadIdx.x;
  {
    const uint4* ws = (const uint4*)Wswz;
    uint4* wd = (uint4*)wt;
#pragma unroll
    for (int i = t; i < 128 * KD / 8; i += 256) wd[i] = ws[i];
  }
  sred[t] = 0.f;
  __syncthreads();
  int wave = t >> 6, lane = t & 63;
  int r0 = lane & 15, kg = lane >> 4;
  float cs[8], cq[8];
#pragma unroll
  for (int n = 0; n < 8; ++n) { cs[n] = 0.f; cq[n] = 0.f; }
  int strip = blockIdx.x * 4 + wave;
  if (strip < NSTRIP) {
    const float* arow = A + (size_t)(strip * 16 + r0) * KD + kg * 8;
    short8 af[KCH];
#pragma unroll
    for (int kk = 0; kk < KCH; ++kk) {
      float4 a0 = *(const float4*)(arow + kk * 32);
      float4 a1 = *(const float4*)(arow + kk * 32 + 4);
      short8 v;
      v[0] = f2bf(a0.x); v[1] = f2bf(a0.y); v[2] = f2bf(a0.z); v[3] = f2bf(a0.w);
      v[4] = f2bf(a1.x); v[5] = f2bf(a1.y); v[6] = f2bf(a1.z); v[7] = f2bf(a1.w);
      af[kk] = v;
    }
    f32x4 acc[8];
#pragma unroll
    for (int n = 0; n < 8; ++n) acc[n] = (f32x4){0.f, 0.f, 0.f, 0.f};
#pragma unroll
    for (int kk = 0; kk < KCH; ++kk) {
      int kb = kk * 32 + kg * 8;
#pragma unroll
      for (int n = 0; n < 8; ++n) {
        int c = n * 16 + r0;
        short8 bf = *(const short8*)(wt + c * KD + (kb ^ ((c & 7) << 3)));
        acc[n] = MFMA(af[kk], bf, acc[n]);
      }
    }
    u16* trow = T + (size_t)(strip * 16 + kg * 4) * HD;
#pragma unroll
    for (int n = 0; n < 8; ++n) {
#pragma unroll
      for (int j = 0; j < 4; ++j) {
        float v = acc[n][j];
        trow[(size_t)j * HD + n * 16 + r0] = (u16)f2bf(v);
        cs[n] += v;
        cq[n] = fmaf(v, v, cq[n]);
      }
    }
  }
#pragma unroll
  for (int n = 0; n < 8; ++n) {
    cs[n] += __shfl_xor(cs[n], 16); cs[n] += __shfl_xor(cs[n], 32);
    cq[n] += __shfl_xor(cq[n], 16); cq[n] += __shfl_xor(cq[n], 32);
  }
  if (kg == 0) {
#pragma unroll
    for (int n = 0; n < 8; ++n) {
      atomicAdd(&sred[n * 16 + r0], cs[n]);
      atomicAdd(&sred[128 + n * 16 + r0], cq[n]);
    }
  }
  __syncthreads();
  atomicAdd(&stats[t], sred[t]);
}

// ---------------- MFMA matmul (bf16 A) + BN column stats ----------------
__global__ __launch_bounds__(256) void k_mm1(const u16* __restrict__ A,
                                             const u16* __restrict__ Wswz,
                                             u16* __restrict__ T,
                                             float* __restrict__ stats) {
  __shared__ short wt[128 * 128];
  __shared__ float sred[256];
  int t = threadIdx.x;
  {
    const uint4* ws = (const uint4*)Wswz;
    uint4* wd = (uint4*)wt;
#pragma unroll
    for (int i = t; i < 2048; i += 256) wd[i] = ws[i];
  }
  sred[t] = 0.f;
  __syncthreads();
  int wave = t >> 6, lane = t & 63;
  int r0 = lane & 15, kg = lane >> 4;
  float cs[8], cq[8];
#pragma unroll
  for (int n = 0; n < 8; ++n) { cs[n] = 0.f; cq[n] = 0.f; }
  int strip = blockIdx.x * 4 + wave;
  if (strip < NSTRIP) {
    const u16* arow = A + (size_t)(strip * 16 + r0) * HD + kg * 8;
    short8 af[4];
#pragma unroll
    for (int kk = 0; kk < 4; ++kk) af[kk] = *(const short8*)(arow + kk * 32);
    f32x4 acc[8];
#pragma unroll
    for (int n = 0; n < 8; ++n) acc[n] = (f32x4){0.f, 0.f, 0.f, 0.f};
#pragma unroll
    for (int kk = 0; kk < 4; ++kk) {
      int kb = kk * 32 + kg * 8;
#pragma unroll
      for (int n = 0; n < 8; ++n) {
        int c = n * 16 + r0;
        short8 bf = *(const short8*)(wt + c * 128 + (kb ^ ((c & 7) << 3)));
        acc[n] = MFMA(af[kk], bf, acc[n]);
      }
    }
    u16* trow = T + (size_t)(strip * 16 + kg * 4) * HD;
#pragma unroll
    for (int n = 0; n < 8; ++n) {
#pragma unroll
      for (int j = 0; j < 4; ++j) {
        float v = acc[n][j];
        trow[(size_t)j * HD + n * 16 + r0] = (u16)f2bf(v);
        cs[n] += v;
        cq[n] = fmaf(v, v, cq[n]);
      }
    }
  }
#pragma unroll
  for (int n = 0; n < 8; ++n) {
    cs[n] += __shfl_xor(cs[n], 16); cs[n] += __shfl_xor(cs[n], 32);
    cq[n] += __shfl_xor(cq[n], 16); cq[n] += __shfl_xor(cq[n], 32);
  }
  if (kg == 0) {
#pragma unroll
    for (int n = 0; n < 8; ++n) {
      atomicAdd(&sred[n * 16 + r0], cs[n]);
      atomicAdd(&sred[128 + n * 16 + r0], cq[n]);
    }
  }
  __syncthreads();
  atomicAdd(&stats[t], sred[t]);
}

// BN-apply + relu (bf16 T in) -> bf16 h
__global__ __launch_bounds__(256) void k_bnrelu(const u16* __restrict__ T,
                                                const float* __restrict__ stats,
                                                const float* __restrict__ g,
                                                const float* __restrict__ b,
                                                u16* __restrict__ Hobf) {
  __shared__ float a_s[HD], b_s[HD];
  int t = threadIdx.x;
  if (t < HD) {
    float mean = stats[t] * (1.f / NN);
    float var = stats[HD + t] * (1.f / NN) - mean * mean;
    float a = g[t] * rsqrtf(var + LN_EPS);
    a_s[t] = a;
    b_s[t] = b[t] - mean * a;
  }
  __syncthreads();
  size_t i4 = ((size_t)blockIdx.x * 256 + t) * 4;
  if (i4 >= (size_t)NN * HD) return;
  int c = (int)(i4 & (HD - 1));
  uint2 rw = *(const uint2*)(T + i4);
  float ox = fmaxf(fmaf(a_s[c], bflo(rw.x), b_s[c]), 0.f);
  float oy = fmaxf(fmaf(a_s[c + 1], bfhi(rw.x), b_s[c + 1]), 0.f);
  float oz = fmaxf(fmaf(a_s[c + 2], bflo(rw.y), b_s[c + 2]), 0.f);
  float ow = fmaxf(fmaf(a_s[c + 3], bfhi(rw.y), b_s[c + 3]), 0.f);
  uint2 w;
  w.x = (unsigned)(u16)f2bf(ox) | ((unsigned)(u16)f2bf(oy) << 16);
  w.y = (unsigned)(u16)f2bf(oz) | ((unsigned)(u16)f2bf(ow) << 16);
  *(uint2*)(Hobf + i4) = w;
}

// ---------------- GINE aggregation: pure bf16 gather-sum + EAGG + self (8x unroll) ----------------
__global__ __launch_bounds__(256) void k_agg(const u16* __restrict__ hbf,
                                             const u16* __restrict__ eagg,
                                             const int* __restrict__ rowptr,
                                             const int* __restrict__ src_perm,
                                             const float* __restrict__ epsp, int l,
                                             u16* __restrict__ zout) {
  int t = threadIdx.x;
  int wave = t >> 6, lane = t & 63;
  int node = blockIdx.x * 4 + wave;
  if (node >= NN) return;
  int p0 = rowptr[node], p1 = rowptr[node + 1];
  float ax = 0.f, ay = 0.f;
  int p = p0;
  for (; p + 7 < p1; p += 8) {
    int s[8];
#pragma unroll
    for (int i = 0; i < 8; ++i) s[i] = src_perm[p + i];
    unsigned h[8];
#pragma unroll
    for (int i = 0; i < 8; ++i)
      h[i] = *(const unsigned*)(hbf + (size_t)s[i] * HD + 2 * lane);
#pragma unroll
    for (int i = 0; i < 8; ++i) {
      ax += bflo(h[i]);
      ay += bfhi(h[i]);
    }
  }
  for (; p + 3 < p1; p += 4) {
    int s0 = src_perm[p], s1 = src_perm[p + 1], s2 = src_perm[p + 2],
        s3 = src_perm[p + 3];
    unsigned h0 = *(const unsigned*)(hbf + (size_t)s0 * HD + 2 * lane);
    unsigned h1 = *(const unsigned*)(hbf + (size_t)s1 * HD + 2 * lane);
    unsigned h2 = *(const unsigned*)(hbf + (size_t)s2 * HD + 2 * lane);
    unsigned h3 = *(const unsigned*)(hbf + (size_t)s3 * HD + 2 * lane);
    ax += (bflo(h0) + bflo(h1)) + (bflo(h2) + bflo(h3));
    ay += (bfhi(h0) + bfhi(h1)) + (bfhi(h2) + bfhi(h3));
  }
  for (; p < p1; ++p) {
    int s0 = src_perm[p];
    unsigned h0 = *(const unsigned*)(hbf + (size_t)s0 * HD + 2 * lane);
    ax += bflo(h0);
    ay += bfhi(h0);
  }
  float e1 = 1.f + epsp[l];
  unsigned hs = *(const unsigned*)(hbf + (size_t)node * HD + 2 * lane);
  unsigned eg = *(const unsigned*)(eagg + (size_t)node * HD + 2 * lane);
  float zx = fmaf(e1, bflo(hs), ax + bflo(eg));
  float zy = fmaf(e1, bfhi(hs), ay + bfhi(eg));
  unsigned zo = (unsigned)(u16)f2bf(zx) | ((unsigned)(u16)f2bf(zy) << 16);
  *(unsigned*)(zout + (size_t)node * HD + 2 * lane) = zo;
}

// ---------------- BN-apply + MFMA matmul2 + LN + residual (all bf16) ----------------
__global__ __launch_bounds__(256) void k_mm2(const u16* __restrict__ T,
                                             const float* __restrict__ stats,
                                             const float* __restrict__ bng,
                                             const float* __restrict__ bnb,
                                             const u16* __restrict__ Wswz,
                                             const float* __restrict__ b2,
                                             const float* __restrict__ lng,
                                             const float* __restrict__ lnb,
                                             const u16* __restrict__ hprevb,
                                             u16* __restrict__ houtbf) {
  __shared__ short wt[128 * 128];
  __shared__ float abl[256];
  int t = threadIdx.x;
  {
    const uint4* ws = (const uint4*)Wswz;
    uint4* wd = (uint4*)wt;
#pragma unroll
    for (int i = t; i < 2048; i += 256) wd[i] = ws[i];
  }
  if (t < 128) {
    float mean = stats[t] * (1.f / NN);
    float var = stats[HD + t] * (1.f / NN) - mean * mean;
    float a = bng[t] * rsqrtf(var + LN_EPS);
    abl[t] = a;
    abl[128 + t] = bnb[t] - mean * a;
  }
  __syncthreads();
  int wave = t >> 6, lane = t & 63;
  int r0 = lane & 15, kg = lane >> 4;
  float bc[8], gc[8], bbc[8];
#pragma unroll
  for (int n = 0; n < 8; ++n) {
    int c = n * 16 + r0;
    bc[n] = b2[c];
    gc[n] = lng[c];
    bbc[n] = lnb[c];
  }
  int strip = blockIdx.x * 4 + wave;
  if (strip < NSTRIP) {
    const u16* trow = T + (size_t)(strip * 16 + r0) * HD + kg * 8;
    short8 af[4];
#pragma unroll
    for (int kk = 0; kk < 4; ++kk) {
      int kb = kk * 32 + kg * 8;
      uint4 rw = *(const uint4*)(trow + kk * 32);
      float f0 = bflo(rw.x), f1 = bfhi(rw.x), f2 = bflo(rw.y), f3 = bfhi(rw.y);
      float f4 = bflo(rw.z), f5 = bfhi(rw.z), f6 = bflo(rw.w), f7 = bfhi(rw.w);
      short8 v;
      v[0] = f2bf(fmaxf(fmaf(abl[kb + 0], f0, abl[128 + kb + 0]), 0.f));
      v[1] = f2bf(fmaxf(fmaf(abl[kb + 1], f1, abl[128 + kb + 1]), 0.f));
      v[2] = f2bf(fmaxf(fmaf(abl[kb + 2], f2, abl[128 + kb + 2]), 0.f));
      v[3] = f2bf(fmaxf(fmaf(abl[kb + 3], f3, abl[128 + kb + 3]), 0.f));
      v[4] = f2bf(fmaxf(fmaf(abl[kb + 4], f4, abl[128 + kb + 4]), 0.f));
      v[5] = f2bf(fmaxf(fmaf(abl[kb + 5], f5, abl[128 + kb + 5]), 0.f));
      v[6] = f2bf(fmaxf(fmaf(abl[kb + 6], f6, abl[128 + kb + 6]), 0.f));
      v[7] = f2bf(fmaxf(fmaf(abl[kb + 7], f7, abl[128 + kb + 7]), 0.f));
      af[kk] = v;
    }
    f32x4 acc[8];
#pragma unroll
    for (int n = 0; n < 8; ++n) acc[n] = (f32x4){0.f, 0.f, 0.f, 0.f};
#pragma unroll
    for (int kk = 0; kk < 4; ++kk) {
      int kb = kk * 32 + kg * 8;
#pragma unroll
      for (int n = 0; n < 8; ++n) {
        int c = n * 16 + r0;
        short8 bf = *(const short8*)(wt + c * 128 + (kb ^ ((c & 7) << 3)));
        acc[n] = MFMA(af[kk], bf, acc[n]);
      }
    }
#pragma unroll
    for (int j = 0; j < 4; ++j) {
      float s = 0.f, sq = 0.f;
#pragma unroll
      for (int n = 0; n < 8; ++n) {
        float v = acc[n][j] + bc[n];
        acc[n][j] = v;
        s += v;
        sq = fmaf(v, v, sq);
      }
      s += __shfl_xor(s, 1); sq += __shfl_xor(sq, 1);
      s += __shfl_xor(s, 2); sq += __shfl_xor(sq, 2);
      s += __shfl_xor(s, 4); sq += __shfl_xor(sq, 4);
      s += __shfl_xor(s, 8); sq += __shfl_xor(sq, 8);
      float mu = s * (1.f / HD);
      float var = sq * (1.f / HD) - mu * mu;
      float rs = rsqrtf(var + LN_EPS);
      size_t rb = (size_t)(strip * 16 + kg * 4 + j) * HD;
      const u16* hp = hprevb + rb;
      u16* hob = houtbf + rb;
#pragma unroll
      for (int n = 0; n < 8; ++n) {
        int c = n * 16 + r0;
        float o = fmaxf(fmaf(gc[n], (acc[n][j] - mu) * rs, bbc[n]) + bf1(hp[c]), 0.f);
        hob[c] = (u16)f2bf(o);
      }
    }
  }
}

// ---------------- JK attention (bf16 in, bf16 out; combine from registers) ----------------
__global__ __launch_bounds__(256) void k_jk(const u16* __restrict__ hb1,
                                            const u16* __restrict__ hb2,
                                            const u16* __restrict__ hb3,
                                            const u16* __restrict__ Wswz,
                                            const float* __restrict__ b1,
                                            const float* __restrict__ w2,
                                            const float* __restrict__ b2,
                                            u16* __restrict__ xn) {
  __shared__ short wt[64 * 128];
  __shared__ float elds[4][3][16];
  int t = threadIdx.x;
  {
    const uint4* ws = (const uint4*)Wswz;
    uint4* wd = (uint4*)wt;
#pragma unroll
    for (int i = t; i < 1024; i += 256) wd[i] = ws[i];
  }
  __syncthreads();
  int wave = t >> 6, lane = t & 63;
  int r0 = lane & 15, kg = lane >> 4;
  float jb1[4], w2c[4];
#pragma unroll
  for (int n = 0; n < 4; ++n) {
    jb1[n] = b1[n * 16 + r0];
    w2c[n] = w2[n * 16 + r0];
  }
  float jb2 = b2[0];
  const u16* hbs[3] = {hb1, hb2, hb3};
  int strip = blockIdx.x * 4 + wave;
  if (strip >= NSTRIP) return;
  {
    f32x4 acc[3][4];
    short8 af3[3][4];
#pragma unroll
    for (int l = 0; l < 3; ++l) {
      const u16* arow = hbs[l] + (size_t)(strip * 16 + r0) * HD + kg * 8;
#pragma unroll
      for (int kk = 0; kk < 4; ++kk) af3[l][kk] = *(const short8*)(arow + kk * 32);
#pragma unroll
      for (int n = 0; n < 4; ++n) acc[l][n] = (f32x4){0.f, 0.f, 0.f, 0.f};
#pragma unroll
      for (int kk = 0; kk < 4; ++kk) {
        int kb = kk * 32 + kg * 8;
#pragma unroll
        for (int n = 0; n < 4; ++n) {
          int c = n * 16 + r0;
          short8 bf = *(const short8*)(wt + c * 128 + (kb ^ ((c & 7) << 3)));
          acc[l][n] = MFMA(af3[l][kk], bf, acc[l][n]);
        }
      }
    }
#pragma unroll
    for (int j = 0; j < 4; ++j) {
      float sc[3];
#pragma unroll
      for (int l = 0; l < 3; ++l) {
        float p = 0.f;
#pragma unroll
        for (int n = 0; n < 4; ++n)
          p = fmaf(fmaxf(acc[l][n][j] + jb1[n], 0.f), w2c[n], p);
        p += __shfl_xor(p, 1);
        p += __shfl_xor(p, 2);
        p += __shfl_xor(p, 4);
        p += __shfl_xor(p, 8);
        sc[l] = p + jb2;
      }
      float m = fmaxf(sc[0], fmaxf(sc[1], sc[2]));
      float e0 = expf(sc[0] - m), e1 = expf(sc[1] - m), e2 = expf(sc[2] - m);
      float inv = 1.f / (e0 + e1 + e2);
      if (r0 == j) {
        elds[wave][0][kg * 4 + j] = e0 * inv;
        elds[wave][1][kg * 4 + j] = e1 * inv;
        elds[wave][2][kg * 4 + j] = e2 * inv;
      }
    }
    float e0r = elds[wave][0][r0];
    float e1r = elds[wave][1][r0];
    float e2r = elds[wave][2][r0];
    size_t rowb = (size_t)(strip * 16 + r0) * HD + kg * 8;
#pragma unroll
    for (int kk = 0; kk < 4; ++kk) {
      uint4 ow;
      unsigned owp[4];
#pragma unroll
      for (int h = 0; h < 4; ++h) {
        float v0 = e0r * bf1((u16)af3[0][kk][2 * h]) + e1r * bf1((u16)af3[1][kk][2 * h]) +
                   e2r * bf1((u16)af3[2][kk][2 * h]);
        float v1 = e0r * bf1((u16)af3[0][kk][2 * h + 1]) +
                   e1r * bf1((u16)af3[1][kk][2 * h + 1]) +
                   e2r * bf1((u16)af3[2][kk][2 * h + 1]);
        owp[h] = (unsigned)(u16)f2bf(v0) | ((unsigned)(u16)f2bf(v1) << 16);
      }
      ow.x = owp[0]; ow.y = owp[1]; ow.z = owp[2]; ow.w = owp[3];
      *(uint4*)(xn + rowb + kk * 32) = ow;
    }
  }
}

// ---------------- graph pooling stage 1 ----------------
__device__ __forceinline__ void seg_bounds(const int* batch, int g, int& start, int& end) {
  int lo = 0, hi = NN;
  while (lo < hi) {
    int mid = (lo + hi) >> 1;
    if (batch[mid] < g) lo = mid + 1; else hi = mid;
  }
  start = lo;
  lo = start; hi = NN;
  while (lo < hi) {
    int mid = (lo + hi) >> 1;
    if (batch[mid] < g + 1) lo = mid + 1; else hi = mid;
  }
  end = lo;
}

__global__ __launch_bounds__(128) void k_pool1(const u16* __restrict__ xn,
                                               const int* __restrict__ batch,
                                               float* __restrict__ partial) {
  int g = blockIdx.x >> 5, ch = blockIdx.x & (PCH - 1), c = threadIdx.x;
  int start, end;
  seg_bounds(batch, g, start, end);
  int len = end - start;
  int n0 = start + (int)((long long)len * ch / PCH);
  int n1 = start + (int)((long long)len * (ch + 1) / PCH);
  float sum = 0.f, m = -INFINITY;
  for (int n = n0; n < n1; ++n) {
    float v = bf1(xn[(size_t)n * HD + c]);
    sum += v;
    m = fmaxf(m, v);
  }
  partial[((size_t)(g * PCH + ch) * 2 + 0) * HD + c] = sum;
  partial[((size_t)(g * PCH + ch) * 2 + 1) * HD + c] = m;
}

// ---------------- fused tail: pool2 + te-LN + concat-LN + classifier matmul ----------------
__global__ __launch_bounds__(576) void k_tail(
    const float* __restrict__ partial, const int* __restrict__ batch,
    const float* __restrict__ teacc, const float* __restrict__ tf_b,
    const float* __restrict__ tf_lng, const float* __restrict__ tf_lnb,
    const float* __restrict__ gfeat, const float* __restrict__ gf_w,
    const float* __restrict__ gf_b, const float* __restrict__ pre_lng,
    const float* __restrict__ pre_lnb, const float* __restrict__ cls_w1,
    const float* __restrict__ cls_b1, float* __restrict__ cw) {
  int g = blockIdx.x, t = threadIdx.x;
  __shared__ float ssum[128], smx[128], tearr[128], gfarr[32], rowb[CDIM];
  __shared__ float wsum[9], wsq[9], tred[4];
  __shared__ float cnt_s, mu_s, rs_s, tmu_s, trs_s;
  if (t < 128) {
    float sum = 0.f, m = -INFINITY;
    for (int ch = 0; ch < PCH; ++ch) {
      sum += partial[((size_t)(g * PCH + ch) * 2 + 0) * HD + t];
      m = fmaxf(m, partial[((size_t)(g * PCH + ch) * 2 + 1) * HD + t]);
    }
    ssum[t] = sum;
    smx[t] = m;
  } else if (t < 256) {
    int c = t - 128;
    tearr[c] = teacc[g * HD + c] + tf_b[c];
  } else if (t < 288) {
    int c = t - 256;
    float a = gf_b[c];
#pragma unroll
    for (int k = 0; k < NSD; ++k) a = fmaf(gfeat[g * NSD + k], gf_w[k * 32 + c], a);
    gfarr[c] = a;
  } else if (t == 544) {
    int s0, e0;
    seg_bounds(batch, g, s0, e0);
    cnt_s = fmaxf((float)(e0 - s0), 1.f);
  }
  __syncthreads();
  // te layer-norm over tearr[128] (waves 0-1)
  {
    int wave = t >> 6, lane = t & 63;
    if (t < 128) {
      float v = tearr[t];
      float sv = v, sq = v * v;
#pragma unroll
      for (int o = 32; o; o >>= 1) {
        sv += __shfl_down(sv, o);
        sq += __shfl_down(sq, o);
      }
      if (lane == 0) {
        tred[wave] = sv;
        tred[2 + wave] = sq;
      }
    }
  }
  __syncthreads();
  if (t == 0) {
    float tot = tred[0] + tred[1], tot2 = tred[2] + tred[3];
    float mu = tot * (1.f / HD);
    tmu_s = mu;
    trs_s = rsqrtf(tot2 * (1.f / HD) - mu * mu + LN_EPS);
  }
  __syncthreads();
  if (t < 128)
    tearr[t] = fmaxf(fmaf(tf_lng[t], (tearr[t] - tmu_s) * trs_s, tf_lnb[t]), 0.f);
  __syncthreads();
  // concat + pre-LN over 544
  float v = 0.f;
  if (t < 128) v = ssum[t] / cnt_s;
  else if (t < 256) v = smx[t - 128];
  else if (t < 384) v = ssum[t - 256];
  else if (t < 416) v = gfarr[t - 384];
  else if (t < CDIM) v = tearr[t - 416];
  {
    int wave = t >> 6, lane = t & 63;
    float sv = (t < CDIM) ? v : 0.f;
    float ss = sv, sq = sv * sv;
#pragma unroll
    for (int o = 32; o; o >>= 1) {
      ss += __shfl_down(ss, o);
      sq += __shfl_down(sq, o);
    }
    if (lane == 0) {
      wsum[wave] = ss;
      wsq[wave] = sq;
    }
  }
  __syncthreads();
  if (t == 0) {
    float a = 0.f, bq = 0.f;
    for (int i = 0; i < 9; ++i) {
      a += wsum[i];
      bq += wsq[i];
    }
    float mu = a * (1.f / CDIM);
    mu_s = mu;
    rs_s = rsqrtf(bq * (1.f / CDIM) - mu * mu + LN_EPS);
  }
  __syncthreads();
  if (t < CDIM) rowb[t] = fmaf(pre_lng[t], (v - mu_s) * rs_s, pre_lnb[t]);
  __syncthreads();
  if (t < 128) {
    float acc = cls_b1[t];
    for (int k = 0; k < CDIM; ++k) acc = fmaf(rowb[k], cls_w1[(size_t)k * HD + t], acc);
    cw[g * HD + t] = acc;
  }
}

// ---------------- final BN + logits ----------------
__global__ __launch_bounds__(128) void k_head(const float* __restrict__ cw,
                                              const float* __restrict__ bng,
                                              const float* __restrict__ bnb,
                                              const float* __restrict__ w2,
                                              const float* __restrict__ b2,
                                              float* __restrict__ out) {
  __shared__ float act[HD * NG];
  int c = threadIdx.x;
  float sum = 0.f, ssq = 0.f;
  float vals[NG];
#pragma unroll
  for (int g = 0; g < NG; ++g) {
    float v = cw[g * HD + c];
    vals[g] = v;
    sum += v;
    ssq = fmaf(v, v, ssq);
  }
  float mu = sum * (1.f / NG);
  float var = ssq * (1.f / NG) - mu * mu;
  float a = bng[c] * rsqrtf(var + LN_EPS);
  float bb = bnb[c] - mu * a;
#pragma unroll
  for (int g = 0; g < NG; ++g) act[c * NG + g] = fmaxf(fmaf(a, vals[g], bb), 0.f);
  __syncthreads();
  if (c < NG) {
    float acc = b2[0];
    for (int k = 0; k < HD; ++k) acc = fmaf(act[k * NG + c], w2[k], acc);
    out[c] = acc;
  }
}

extern "C" void kernel_launch(void* const* d_in, const int* in_sizes, int n_in,
                              void* d_out, int out_size, void* d_ws, size_t ws_size,
                              hipStream_t stream) {
  (void)in_sizes; (void)n_in; (void)out_size; (void)ws_size;
  const float* x = (const float*)d_in[0];
  const float* edge_attr = (const float*)d_in[1];
  const float* gfeat = (const float*)d_in[2];
  const float* tfidf = (const float*)d_in[3];
  const float* w_in = (const float*)d_in[4];
  const float* g_in = (const float*)d_in[6];
  const float* be_in = (const float*)d_in[7];
  const float* w_e = (const float*)d_in[8];
  const float* b_e = (const float*)d_in[9];
  const float* conv_w1 = (const float*)d_in[10];
  const float* conv_bng = (const float*)d_in[12];
  const float* conv_bnb = (const float*)d_in[13];
  const float* conv_w2 = (const float*)d_in[14];
  const float* conv_b2 = (const float*)d_in[15];
  const float* conv_eps = (const float*)d_in[16];
  const float* conv_lng = (const float*)d_in[17];
  const float* conv_lnb = (const float*)d_in[18];
  const float* jk_w1 = (const float*)d_in[19];
  const float* jk_b1 = (const float*)d_in[20];
  const float* jk_w2 = (const float*)d_in[21];
  const float* jk_b2 = (const float*)d_in[22];
  const float* gf_w = (const float*)d_in[23];
  const float* gf_b = (const float*)d_in[24];
  const float* tf_w = (const float*)d_in[25];
  const float* tf_b = (const float*)d_in[26];
  const float* tf_lng = (const float*)d_in[27];
  const float* tf_lnb = (const float*)d_in[28];
  const float* pre_lng = (const float*)d_in[29];
  const float* pre_lnb = (const float*)d_in[30];
  const float* cls_w1 = (const float*)d_in[31];
  const float* cls_b1 = (const float*)d_in[32];
  const float* cls_bng = (const float*)d_in[33];
  const float* cls_bnb = (const float*)d_in[34];
  const float* cls_w2 = (const float*)d_in[35];
  const float* cls_b2 = (const float*)d_in[36];
  const int* edge_index = (const int*)d_in[37];
  const int* batch = (const int*)d_in[38];
  const int* srcp = edge_index;
  const int* dstp = edge_index + NE;
  float* out = (float*)d_out;

  char* ws = (char*)d_ws;
  size_t off = 0;
  auto alloc = [&](size_t bytes) -> void* {
    void* p = ws + off;
    off += (bytes + 255) & ~(size_t)255;
    return p;
  };
  int* cnt = (int*)alloc((size_t)NN * 4);
  int* rowptr = (int*)alloc((size_t)(NN + 1) * 4);
  int* nextp = (int*)alloc((size_t)NN * 4);
  int* tileSum = (int*)alloc(64 * 4);
  int* tileOff = (int*)alloc(64 * 4);
  int* src_perm = (int*)alloc((size_t)NE * 4);
  u16* attr_bf = (u16*)alloc((size_t)NE * DE * 2);
  u16* wpre = (u16*)alloc((size_t)WPRE_TOTAL * 2);
  u16* eaggb = (u16*)alloc((size_t)NN * HD * 2);
  u16* zb = (u16*)alloc((size_t)NN * HD * 2);
  u16* tbuf = (u16*)alloc((size_t)NN * HD * 2);
  u16* hbB[4];
  for (int i = 0; i < 4; ++i) hbB[i] = (u16*)alloc((size_t)NN * HD * 2);
  float* statsAll = (float*)alloc(4 * 256 * 4);
  float* partial = (float*)alloc((size_t)NG * PCH * 2 * HD * 4);
  float* teacc = (float*)alloc((size_t)NG * HD * 4);
  float* cwbuf = (float*)alloc((size_t)NG * HD * 4);
  u16* xn = zb;  // zb dead after last k_mm1

  hipMemsetAsync(cnt, 0, (size_t)NN * 4, stream);
  hipMemsetAsync(statsAll, 0, 4 * 256 * 4, stream);

  k_prep<<<CNT_BLOCKS + WCVT_BLOCKS, 256, 0, stream>>>(dstp, cnt, w_in, conv_w1, conv_w2,
                                                       jk_w1, wpre);
  k_te2<<<NG, 512, 0, stream>>>(tfidf, tf_w, teacc);
  k_scan1<<<NTILES, 256, 0, stream>>>(cnt, rowptr, tileSum);
  k_scan2<<<1, 64, 0, stream>>>(tileSum, tileOff, rowptr);
  k_scan3<<<(NN + 255) / 256, 256, 0, stream>>>(tileOff, rowptr, nextp);
  k_fill<<<(NE / 2 + 255) / 256, 256, 0, stream>>>(srcp, dstp, edge_attr, nextp,
                                                   src_perm, attr_bf);
  k_eagg<<<(NN + 3) / 4, 256, 0, stream>>>(rowptr, attr_bf, w_e, b_e, eaggb);

  k_mm1f<DIN><<<MM_GRID, 256, 0, stream>>>(x, wpre + OFF_IN, tbuf, statsAll);
  k_bnrelu<<<(NN * HD / 4 + 255) / 256, 256, 0, stream>>>(tbuf, statsAll, g_in, be_in,
                                                          hbB[0]);

  for (int l = 0; l < NL; ++l) {
    k_agg<<<(NN + 3) / 4, 256, 0, stream>>>(hbB[l], eaggb, rowptr, src_perm, conv_eps, l,
                                            zb);
    k_mm1<<<MM_GRID, 256, 0, stream>>>(zb, wpre + OFF_W1 + l * 16384, tbuf,
                                       statsAll + (1 + l) * 256);
    k_mm2<<<MM_GRID, 256, 0, stream>>>(tbuf, statsAll + (1 + l) * 256, conv_bng + l * HD,
                                       conv_bnb + l * HD, wpre + OFF_W2 + l * 16384,
                                       conv_b2 + l * HD, conv_lng + l * HD,
                                       conv_lnb + l * HD, hbB[l], hbB[l + 1]);
  }

  k_jk<<<MM_GRID, 256, 0, stream>>>(hbB[1], hbB[2], hbB[3], wpre + OFF_JK, jk_b1, jk_w2,
                                    jk_b2, xn);
  k_pool1<<<NG * PCH, 128, 0, stream>>>(xn, batch, partial);
  k_tail<<<NG, 576, 0, stream>>>(partial, batch, teacc, tf_b, tf_lng, tf_lnb, gfeat,
                                 gf_w, gf_b, pre_lng, pre_lnb, cls_w1, cls_b1, cwbuf);
  k_head<<<1, 128, 0, stream>>>(cwbuf, cls_bng, cls_bnb, cls_w2, cls_b2, out);
}